// Round 23
// baseline (67.430 us; speedup 1.0000x reference)
//
#include <hip/hip_runtime.h>
#include <hip/hip_fp16.h>

typedef __attribute__((ext_vector_type(8))) short short8;
typedef __attribute__((ext_vector_type(8))) __bf16 bf16x8;
typedef __attribute__((ext_vector_type(4))) float f32x4;
typedef __attribute__((ext_vector_type(16))) float f32x16;

#define DEV __device__ __forceinline__

DEV unsigned short f2bf(float f) {
    unsigned int u = __float_as_uint(f);
    return (unsigned short)((u + 0x7FFFu + ((u >> 16) & 1u)) >> 16);
}
DEV float bf2f(unsigned short s) { return __uint_as_float(((unsigned int)s) << 16); }
DEV bf16x8 asbf(short8 v) { return __builtin_bit_cast(bf16x8, v); }
DEV float ex2(float x) { return __builtin_amdgcn_exp2f(x); }   // bare v_exp_f32
DEV float max3(float a, float b, float c) {
    float d;
    asm("v_max3_f32 %0, %1, %2, %3" : "=v"(d) : "v"(a), "v"(b), "v"(c));
    return d;
}

// async global->LDS, 16B per lane; lds base must be wave-uniform, gsrc per-lane
DEV void gload16(const void* g, void* l) {
    __builtin_amdgcn_global_load_lds(
        (const __attribute__((address_space(1))) unsigned int*)g,
        (__attribute__((address_space(3))) unsigned int*)l, 16, 0, 0);
}

// ---------------- prep kernel (feat cast + weight pack fused; Q/pe in log2 domain) ----------------
// peG2 layout: [hg(8)][4096] dwords; dword = {f16 head hg*2, f16 head hg*2+1}
__global__ __launch_bounds__(256) void k_prep(const float* __restrict__ feat,
                                              const float* __restrict__ qw, const float* __restrict__ qb,
                                              const float* __restrict__ kvw, const float* __restrict__ kvb,
                                              const float* __restrict__ pew, const float* __restrict__ peb,
                                              const float* __restrict__ pret, const float* __restrict__ projw,
                                              unsigned short* __restrict__ featb,
                                              unsigned short* __restrict__ wqkv, float* __restrict__ bqkv,
                                              unsigned short* __restrict__ projwb, unsigned short* __restrict__ peG2) {
    const float l2e = 1.4426950408889634f;
    const float scale = 0.17677669529663687f * 1.4426950408889634f; // (1/sqrt(32)) * log2(e)
    int i0 = blockIdx.x * 256 + threadIdx.x;
    if (i0 < 262144) {                        // feat f32 -> bf16, 8/thread
        const float4* f4 = (const float4*)feat + (size_t)i0 * 2;
        float4 a = f4[0], c = f4[1];
        short8 o;
        o[0] = (short)f2bf(a.x); o[1] = (short)f2bf(a.y);
        o[2] = (short)f2bf(a.z); o[3] = (short)f2bf(a.w);
        o[4] = (short)f2bf(c.x); o[5] = (short)f2bf(c.y);
        o[6] = (short)f2bf(c.z); o[7] = (short)f2bf(c.w);
        ((short8*)featb)[i0] = o;
        return;
    }
    int i = i0 - 262144;
    if (i < 786432) {                         // wqkv [1536][512]; Q rows pre-scaled to log2 domain
        int o = i >> 9, k = i & 511;
        float v = (o < 512) ? qw[(o << 9) + k] * scale : kvw[((o - 512) << 9) + k];
        wqkv[i] = f2bf(v);
    } else if (i < 786432 + 262144) {
        int j = i - 786432;
        projwb[j] = f2bf(projw[j]);
    } else if (i < 786432 + 262144 + 1536) {
        int o = i - (786432 + 262144);
        bqkv[o] = (o < 512) ? qb[o] * scale : kvb[o - 512];
    } else if (i < 786432 + 262144 + 1536 + 65536) { // peG2[h>>1][t] halves, log2 domain
        int j = i - (786432 + 262144 + 1536);
        int t = j >> 4, h = j & 15;
        float s = peb[h];
#pragma unroll
        for (int u = 0; u < 5; u++) s += pret[t * 5 + u] * pew[h * 5 + u];
        peG2[(size_t)(h >> 1) * 8192 + t * 2 + (h & 1)] =
            __builtin_bit_cast(unsigned short, __float2half(s * l2e));
    }
}

// ---------------- QKV GEMM: gload_lds staging + LDS-transposed coalesced epilogue ----------------
__global__ __launch_bounds__(256) void k_qkv(const unsigned short* __restrict__ A,
                                             const unsigned short* __restrict__ Bw,
                                             const float* __restrict__ bias,
                                             unsigned short* __restrict__ Qf,
                                             unsigned short* __restrict__ Kf,
                                             unsigned short* __restrict__ Vf) {
    __shared__ __align__(16) unsigned short As[128 * 64];
    __shared__ __align__(16) unsigned short Bs[64 * 64];
    __shared__ __align__(16) unsigned short Cs[128][78];   // 19.97 KB, stride 39 dwords (odd)
    int tid = threadIdx.x, lane = tid & 63, wid = tid >> 6;
    int m0 = blockIdx.y * 128, n0 = blockIdx.x * 64;
    int wm = wid >> 1, wn = wid & 1;
    int q16 = lane & 15, g = lane >> 4;
    int lr = lane >> 3;
    int lk = ((lane & 7) ^ lr) * 8;
    f32x4 acc[4][2] = {};

    for (int k0 = 0; k0 < 512; k0 += 64) {
#pragma unroll
        for (int i = 0; i < 4; i++) {
            int ch = wid * 4 + i;
            gload16(A + (size_t)(m0 + ch * 8 + lr) * 512 + k0 + lk, As + ch * 512);
        }
#pragma unroll
        for (int i = 0; i < 2; i++) {
            int ch = wid * 2 + i;
            gload16(Bw + (size_t)(n0 + ch * 8 + lr) * 512 + k0 + lk, Bs + ch * 512);
        }
        __syncthreads();
#pragma unroll
        for (int kk = 0; kk < 64; kk += 32) {
            int c8 = (kk >> 3) + g;
            short8 a[4], b[2];
#pragma unroll
            for (int m = 0; m < 4; m++) {
                int row = wm * 64 + m * 16 + q16;
                a[m] = *(const short8*)(As + row * 64 + ((c8 ^ (q16 & 7)) << 3));
            }
#pragma unroll
            for (int n = 0; n < 2; n++) {
                int row = wn * 32 + n * 16 + q16;
                b[n] = *(const short8*)(Bs + row * 64 + ((c8 ^ (q16 & 7)) << 3));
            }
#pragma unroll
            for (int m = 0; m < 4; m++) {
#pragma unroll
                for (int n = 0; n < 2; n++)
                    acc[m][n] = __builtin_amdgcn_mfma_f32_16x16x32_bf16(asbf(a[m]), asbf(b[n]), acc[m][n], 0, 0, 0);
            }
        }
        __syncthreads();
    }

    // ---- epilogue: C -> Cs (bf16) -> 16B coalesced stores into fragment layouts ----
#pragma unroll
    for (int m = 0; m < 4; m++) {
#pragma unroll
        for (int n = 0; n < 2; n++) {
            int colL = wn * 32 + n * 16 + q16;
            float bv = bias[n0 + colL];
#pragma unroll
            for (int r = 0; r < 4; r++) {
                int rowL = wm * 64 + m * 16 + (g << 2) + r;
                Cs[rowL][colL] = f2bf(acc[m][n][r] + bv);
            }
        }
    }
    __syncthreads();
    int bx = blockIdx.x;
    if (bx < 8) {
        // Q block: 1024 horizontal 16B segments (8 consecutive d of one token)
#pragma unroll
        for (int s2 = 0; s2 < 4; s2++) {
            int seg = tid + 256 * s2;
            int row = seg >> 3, dseg = seg & 7;
            short8 v = *(const short8*)(&Cs[row][dseg * 8]);
            int rowg = m0 + row;
            int batch = rowg >> 10, nn = rowg & 1023;
            int col = n0 + dseg * 8;
            int h = col >> 5, d = col & 31;
            int bh = (batch << 4) + h;
            int qt = nn >> 5, q5l = nn & 31;
            int sub = d >> 4, hi2 = (d >> 3) & 1;
            *(short8*)(Qf + ((((size_t)(bh * 32 + qt) * 2 + sub) * 64) + hi2 * 32 + q5l) * 8) = v;
        }
    } else {
        int h = bx - 8;                      // this block covers head h's K (cols 0-31) + V (32-63)
#pragma unroll
        for (int s2 = 0; s2 < 2; s2++) {     // K: horizontal segments
            int seg = tid + 256 * s2;        // 0..511
            int row = seg >> 2, dseg = seg & 3;
            short8 v = *(const short8*)(&Cs[row][dseg * 8]);
            int rowg = m0 + row;
            int batch = rowg >> 10, nn = rowg & 1023;
            int bh = (batch << 4) + h;
            int kt = nn >> 6, ks = (nn >> 5) & 1, q5l = nn & 31;
            int d = dseg * 8;
            int half = d >> 4, hi2 = (d >> 3) & 1;
            *(short8*)(Kf + ((((size_t)((bh * 16 + kt) * 2 + ks) * 2 + half) * 64) + hi2 * 32 + q5l) * 8) = v;
        }
#pragma unroll
        for (int s2 = 0; s2 < 2; s2++) {     // V: vertical segments (8 consecutive tokens, one d)
            int seg = tid + 256 * s2;        // 0..511
            int c = seg & 31, row0 = (seg >> 5) * 8;
            unsigned short tmp[8];
#pragma unroll
            for (int i2 = 0; i2 < 8; i2++) tmp[i2] = Cs[row0 + i2][32 + c];
            int rowg = m0 + row0;
            int batch = rowg >> 10, nn = rowg & 1023;    // aligned to 8
            int bh = (batch << 4) + h;
            int kt = nn >> 6, ks = (nn >> 5) & 1, nb = nn & 31;
            int half = nb >> 4, hi2 = (nb >> 3) & 1;
            *(short8*)(Vf + ((((size_t)((bh * 16 + kt) * 2 + ks) * 2 + half) * 64) + hi2 * 32 + c) * 8) =
                *(short8*)tmp;
        }
    }
}

// ---------------- fused attention: double-buffered posS2, 1 barrier/step ----------------
// grid 1024: b=bid&3, qt=(bid>>2)&31, hg=(bid>>7)&7
// 256 threads = 4 waves; wave w: head = hg*2+(w&1), khalf = w>>1
__global__ __launch_bounds__(256, 4) void k_attn(const unsigned short* __restrict__ Qf,
                                                 const unsigned short* __restrict__ Kf,
                                                 const unsigned short* __restrict__ Vf,
                                                 const int* __restrict__ pe_idx,
                                                 const unsigned* __restrict__ peG2,
                                                 const float* __restrict__ blank_k,
                                                 const float* __restrict__ blank_v,
                                                 unsigned short* __restrict__ attnO) {
    __shared__ unsigned peT2[4096];                         // 16 KB (read-only after init)
    __shared__ __align__(16) unsigned posS2[2][32 * 132];   // 2 x 16.9 KB double buffer

    int tid = threadIdx.x, lane = tid & 63, w = tid >> 6;
    int q5 = lane & 31, hi = lane >> 5;
    int bid = blockIdx.x;
    int b = bid & 3, qt = (bid >> 2) & 31, hg = (bid >> 7) & 7;
    int q0 = qt * 32;
    int hl = w & 1, khalf = w >> 1;
    int head = hg * 2 + hl, bh = (b << 4) + head;

    // stage peT2 (one-time): 16 coalesced b32 per thread
    {
        const unsigned* pg = peG2 + (size_t)hg * 4096;
#pragma unroll
        for (int j2 = 0; j2 < 16; j2++) {
            int r = tid + 256 * j2;
            peT2[r] = pg[r];
        }
    }

    // staging map: thread -> q row sq, k-octet kg; 4 int4 idx loads cover 128 k
    int sq = tid >> 3, kg = tid & 7;
    const int* pibase = pe_idx + ((size_t)((b << 10) + q0 + sq)) * 1024;

    short8 qf[2];
    float lb_, m_run, l_run;
    f32x16 accO = {};

    {
        const unsigned short* qb_ = Qf + ((size_t)(bh * 32 + qt) * 2) * 512 + lane * 8;
        qf[0] = *(const short8*)(qb_);
        qf[1] = *(const short8*)(qb_ + 512);
        float dot = 0.f;
#pragma unroll
        for (int sub = 0; sub < 2; sub++) {
            const float* bk = blank_k + head * 32 + sub * 16 + hi * 8;
#pragma unroll
            for (int t = 0; t < 8; t++) dot += bf2f((unsigned short)qf[sub][t]) * bk[t];
        }
        dot += __shfl_xor(dot, 32, 64);
        lb_ = dot;                           // log2 domain (qf pre-scaled by log2e)
        m_run = (khalf == 0) ? dot : -1e30f;
        l_run = (khalf == 0) ? 1.0f : 0.0f;
    }

    // prologue: id4(0) -> gather gg(0) -> write posS2[0]; load id4(1); single barrier
    int4 id4[4];
    unsigned gg[4][4];
#pragma unroll
    for (int s = 0; s < 4; s++) {
        int col = (s < 2) ? (kg * 4 + 32 * s) : (512 + kg * 4 + 32 * (s - 2));
        id4[s] = *(const int4*)(pibase + col);
    }
    __syncthreads();   // peT2 ready
#pragma unroll
    for (int s = 0; s < 4; s++) {
        gg[s][0] = peT2[id4[s].x]; gg[s][1] = peT2[id4[s].y];
        gg[s][2] = peT2[id4[s].z]; gg[s][3] = peT2[id4[s].w];
    }
#pragma unroll
    for (int s = 0; s < 4; s++) {
        uint4 wv = {gg[s][0], gg[s][1], gg[s][2], gg[s][3]};
        *(uint4*)&posS2[0][sq * 132 + kg * 4 + 32 * s] = wv;
    }
#pragma unroll
    for (int s = 0; s < 4; s++) {          // id4 <- indices for step 1
        int col = (s < 2) ? (64 + kg * 4 + 32 * s) : (512 + 64 + kg * 4 + 32 * (s - 2));
        id4[s] = *(const int4*)(pibase + col);
    }
    __syncthreads();   // posS2[0] ready

    for (int step = 0; step < 8; step++) {
        int cur = step & 1;
        int ktg = khalf * 8 + step;
        // S^T = K x Q^T, pos folded into MFMA C-init; rows k=(r&3)+8*(r>>2)+4*hi, col q=q5
        f32x16 st[2];
#pragma unroll
        for (int ks = 0; ks < 2; ks++) {
            f32x16 p;
#pragma unroll
            for (int rr = 0; rr < 4; rr++) {
                uint4 v = *(const uint4*)&posS2[cur][q5 * 132 + khalf * 64 + ks * 32 + rr * 8 + 4 * hi];
                unsigned pv[4] = {v.x, v.y, v.z, v.w};
#pragma unroll
                for (int c = 0; c < 4; c++) {
                    __half2 h2 = __builtin_bit_cast(__half2, pv[c]);
                    p[rr * 4 + c] = hl ? __high2float(h2) : __low2float(h2);
                }
            }
            const unsigned short* kp = Kf + ((size_t)((bh * 16 + ktg) * 2 + ks) * 2) * 512 + lane * 8;
            short8 kf0 = *(const short8*)(kp);
            short8 kf1 = *(const short8*)(kp + 512);
            __builtin_amdgcn_s_setprio(1);
            st[ks] = __builtin_amdgcn_mfma_f32_32x32x16_bf16(asbf(kf0), asbf(qf[0]), p, 0, 0, 0);
            st[ks] = __builtin_amdgcn_mfma_f32_32x32x16_bf16(asbf(kf1), asbf(qf[1]), st[ks], 0, 0, 0);
            __builtin_amdgcn_s_setprio(0);
        }
        // staging for step+1 fully inside compute phase: gather + write buf cur^1
        // (safe: cur^1 was last read in step-1, all waves passed the boundary barrier)
        if (step < 7) {
#pragma unroll
            for (int s = 0; s < 4; s++) {
                gg[s][0] = peT2[id4[s].x]; gg[s][1] = peT2[id4[s].y];
                gg[s][2] = peT2[id4[s].z]; gg[s][3] = peT2[id4[s].w];
            }
#pragma unroll
            for (int s = 0; s < 4; s++) {
                uint4 wv = {gg[s][0], gg[s][1], gg[s][2], gg[s][3]};
                *(uint4*)&posS2[cur ^ 1][sq * 132 + kg * 4 + 32 * s] = wv;
            }
            if (step < 6) {
#pragma unroll
                for (int s = 0; s < 4; s++) {
                    int col = (s < 2) ? ((step + 2) * 64 + kg * 4 + 32 * s)
                                      : (512 + (step + 2) * 64 + kg * 4 + 32 * (s - 2));
                    id4[s] = *(const int4*)(pibase + col);
                }
            }
        }
        // tile max: v_max3 tree (32 vals -> 11 -> 4 -> 1)
        float tm[11];
#pragma unroll
        for (int i = 0; i < 8; i++) tm[i] = max3(st[0][i], st[0][i + 8], st[1][i]);
        tm[8] = max3(st[1][8], st[1][9], st[1][10]);
        tm[9] = max3(st[1][11], st[1][12], st[1][13]);
        tm[10] = fmaxf(st[1][14], st[1][15]);
        float a0 = max3(tm[0], tm[1], tm[2]);
        float a1 = max3(tm[3], tm[4], tm[5]);
        float a2 = max3(tm[6], tm[7], tm[8]);
        float a3 = fmaxf(tm[9], tm[10]);
        float mx = fmaxf(max3(a0, a1, a2), a3);
        mx = fmaxf(mx, __shfl_xor(mx, 32, 64));
        // defer-max (T13), log2 domain: P bounded by 2^8
        if (!__all(mx <= m_run + 8.0f)) {
            float mn = fmaxf(m_run, mx);
            float fac = ex2(m_run - mn);
            m_run = mn;
            l_run *= fac;
#pragma unroll
            for (int r = 0; r < 16; r++) {
                int qrow = (r & 3) + 8 * (r >> 2) + 4 * hi;
                float facr = __shfl(fac, qrow, 64);
                accO[r] *= facr;
            }
        }
#pragma unroll
        for (int ks = 0; ks < 2; ks++)
#pragma unroll
            for (int r = 0; r < 16; r++)
                st[ks][r] = ex2(st[ks][r] - m_run);
        // sum: tree reduction
        float ts[16];
#pragma unroll
        for (int i = 0; i < 16; i++) ts[i] = st[0][i] + st[1][i];
#pragma unroll
        for (int i = 0; i < 8; i++) ts[i] += ts[i + 8];
#pragma unroll
        for (int i = 0; i < 4; i++) ts[i] += ts[i + 4];
        float sum = (ts[0] + ts[1]) + (ts[2] + ts[3]);
        sum += __shfl_xor(sum, 32, 64);
        l_run += sum;
        // P -> A-frag via v_cvt_pk_bf16_f32 + permlane32_swap (T12), then PV
#pragma unroll
        for (int ks = 0; ks < 2; ks++) {
            unsigned pk_[8];
#pragma unroll
            for (int i = 0; i < 8; i++) {
                float plo = st[ks][2 * i], phi = st[ks][2 * i + 1];
                asm("v_cvt_pk_bf16_f32 %0, %1, %2" : "=v"(pk_[i]) : "v"(plo), "v"(phi));
            }
            asm("v_permlane32_swap_b32 %0, %1" : "+v"(pk_[0]), "+v"(pk_[2]));
            asm("v_permlane32_swap_b32 %0, %1" : "+v"(pk_[1]), "+v"(pk_[3]));
            asm("v_permlane32_swap_b32 %0, %1" : "+v"(pk_[4]), "+v"(pk_[6]));
            asm("v_permlane32_swap_b32 %0, %1" : "+v"(pk_[5]), "+v"(pk_[7]));
            uint4 u0 = {pk_[0], pk_[1], pk_[2], pk_[3]};
            uint4 u1 = {pk_[4], pk_[5], pk_[6], pk_[7]};
            short8 pa0 = __builtin_bit_cast(short8, u0);
            short8 pa1 = __builtin_bit_cast(short8, u1);
            const unsigned short* vp = Vf + ((size_t)((bh * 16 + ktg) * 2 + ks) * 2) * 512 + lane * 8;
            short8 vf0 = *(const short8*)(vp);
            short8 vf1 = *(const short8*)(vp + 512);
            __builtin_amdgcn_s_setprio(1);
            accO = __builtin_amdgcn_mfma_f32_32x32x16_bf16(asbf(pa0), asbf(vf0), accO, 0, 0, 0);
            accO = __builtin_amdgcn_mfma_f32_32x32x16_bf16(asbf(pa1), asbf(vf1), accO, 0, 0, 0);
            __builtin_amdgcn_s_setprio(0);
        }
        __syncthreads();   // boundary: cur fully consumed; cur^1 writes visible
    }

    // ---- in-block split-k combine (posS2[0] reused as scratch), log2 domain ----
    float* fb = (float*)&posS2[0][0];    // comb[hl][lane][17] then mS[2][32], lS[2][32]
    float* mS = fb + 2176;
    float* lS = mS + 64;
    if (khalf == 1) {
#pragma unroll
        for (int r = 0; r < 16; r++)
            fb[(hl * 64 + lane) * 17 + r] = accO[r];
        if (hi == 0) {
            mS[hl * 32 + q5] = m_run;
            lS[hl * 32 + q5] = l_run;
        }
    }
    __syncthreads();
    if (khalf == 0) {
        float mB = mS[hl * 32 + q5], lB = lS[hl * 32 + q5];
        float M = fmaxf(m_run, mB);
        float eA = ex2(m_run - M), eB = ex2(mB - M);
        float L = l_run * eA + lB * eB;
        float inv = 1.0f / L;
        float bw = ex2(lb_ - M) * inv;
        float bv = blank_v[head * 32 + q5];
#pragma unroll
        for (int r = 0; r < 16; r++) {
            int qrow = (r & 3) + 8 * (r >> 2) + 4 * hi;
            float eA_r = __shfl(eA, qrow, 64);
            float eB_r = __shfl(eB, qrow, 64);
            float inv_r = __shfl(inv, qrow, 64);
            float bw_r = __shfl(bw, qrow, 64);
            float accB = fb[(hl * 64 + lane) * 17 + r];
            float ov = (accO[r] * eA_r + accB * eB_r) * inv_r + bw_r * bv;
            attnO[((size_t)((b << 10) + q0 + qrow)) * 512 + head * 32 + q5] = f2bf(ov);
        }
    }
}

// ---------------- final projection GEMM: 64x64 tiles, grid 512 (2/CU) ----------------
__global__ __launch_bounds__(256) void k_proj(const unsigned short* __restrict__ A,
                                              const unsigned short* __restrict__ Bw,
                                              const float* __restrict__ bias,
                                              float* __restrict__ out) {
    __shared__ __align__(16) unsigned short As[64 * 64];
    __shared__ __align__(16) unsigned short Bs[64 * 64];
    int tid = threadIdx.x, lane = tid & 63, wid = tid >> 6;
    int m0 = blockIdx.y * 64, n0 = blockIdx.x * 64;
    int wm = wid >> 1, wn = wid & 1;
    int q16 = lane & 15, g = lane >> 4;
    int lr = lane >> 3;
    int lk = ((lane & 7) ^ lr) * 8;
    f32x4 acc[2][2] = {};

    for (int k0 = 0; k0 < 512; k0 += 64) {
#pragma unroll
        for (int i = 0; i < 2; i++) {
            int ch = wid * 2 + i;
            gload16(A + (size_t)(m0 + ch * 8 + lr) * 512 + k0 + lk, As + ch * 512);
            gload16(Bw + (size_t)(n0 + ch * 8 + lr) * 512 + k0 + lk, Bs + ch * 512);
        }
        __syncthreads();
#pragma unroll
        for (int kk = 0; kk < 64; kk += 32) {
            int c8 = (kk >> 3) + g;
            short8 a[2], b[2];
#pragma unroll
            for (int m = 0; m < 2; m++) {
                int row = wm * 32 + m * 16 + q16;
                a[m] = *(const short8*)(As + row * 64 + ((c8 ^ (q16 & 7)) << 3));
            }
#pragma unroll
            for (int n = 0; n < 2; n++) {
                int row = wn * 32 + n * 16 + q16;
                b[n] = *(const short8*)(Bs + row * 64 + ((c8 ^ (q16 & 7)) << 3));
            }
#pragma unroll
            for (int m = 0; m < 2; m++) {
#pragma unroll
                for (int n = 0; n < 2; n++)
                    acc[m][n] = __builtin_amdgcn_mfma_f32_16x16x32_bf16(asbf(a[m]), asbf(b[n]), acc[m][n], 0, 0, 0);
            }
        }
        __syncthreads();
    }
#pragma unroll
    for (int m = 0; m < 2; m++) {
#pragma unroll
        for (int n = 0; n < 2; n++) {
            int col = n0 + wn * 32 + n * 16 + q16;
            float bv = bias[col];
#pragma unroll
            for (int r = 0; r < 4; r++) {
                int row = m0 + wm * 32 + m * 16 + (g << 2) + r;
                out[(size_t)row * 512 + col] = acc[m][n][r] + bv;
            }
        }
    }
}

extern "C" void kernel_launch(void* const* d_in, const int* in_sizes, int n_in,
                              void* d_out, int out_size, void* d_ws, size_t ws_size,
                              hipStream_t stream) {
    const float* feat    = (const float*)d_in[0];
    const int*   pe_idx  = (const int*)d_in[3];
    const float* pret    = (const float*)d_in[5];
    const float* qw      = (const float*)d_in[6];
    const float* qb      = (const float*)d_in[7];
    const float* kvw     = (const float*)d_in[8];
    const float* kvb     = (const float*)d_in[9];
    const float* pew     = (const float*)d_in[10];
    const float* peb     = (const float*)d_in[11];
    const float* blank_k = (const float*)d_in[12];
    const float* blank_v = (const float*)d_in[13];
    const float* projw   = (const float*)d_in[14];
    const float* projb   = (const float*)d_in[15];

    char* ws = (char*)d_ws;
    unsigned short* featb  = (unsigned short*)(ws);                  // 4 MB (reused as attnO)
    unsigned short* wqkv   = (unsigned short*)(ws + 4194304);        // 1.5 MB
    unsigned short* projwb = (unsigned short*)(ws + 5767168);        // 0.5 MB
    float*          bqkv   = (float*)(ws + 6291456);                 // 6 KB
    unsigned short* peG2   = (unsigned short*)(ws + 6297600);        // 128 KB
    unsigned short* Qf     = (unsigned short*)(ws + 6428672);        // 4 MB
    unsigned short* Kf     = (unsigned short*)(ws + 10622976);       // 4 MB
    unsigned short* Vf     = (unsigned short*)(ws + 14817280);       // 4 MB
    unsigned short* attnO  = featb;                                  // alias (featb dead after k_qkv)

    k_prep<<<dim3(5382), dim3(256), 0, stream>>>(feat, qw, qb, kvw, kvb, pew, peb, pret, projw,
                                                 featb, wqkv, bqkv, projwb, peG2);
    k_qkv<<<dim3(24, 32), dim3(256), 0, stream>>>(featb, wqkv, bqkv, Qf, Kf, Vf);
    k_attn<<<dim3(1024), dim3(256), 0, stream>>>(Qf, Kf, Vf, pe_idx, (const unsigned*)peG2,
                                                 blank_k, blank_v, attnO);
    k_proj<<<dim3(8, 64), dim3(256), 0, stream>>>(attnO, projwb, projb, (float*)d_out);
}

// Round 24
// 60.988 us; speedup vs baseline: 1.1056x; 1.1056x over previous
//
#include <hip/hip_runtime.h>
#include <hip/hip_fp16.h>

typedef __attribute__((ext_vector_type(8))) short short8;
typedef __attribute__((ext_vector_type(8))) __bf16 bf16x8;
typedef __attribute__((ext_vector_type(4))) float f32x4;
typedef __attribute__((ext_vector_type(16))) float f32x16;

#define DEV __device__ __forceinline__

DEV unsigned short f2bf(float f) {
    unsigned int u = __float_as_uint(f);
    return (unsigned short)((u + 0x7FFFu + ((u >> 16) & 1u)) >> 16);
}
DEV float bf2f(unsigned short s) { return __uint_as_float(((unsigned int)s) << 16); }
DEV bf16x8 asbf(short8 v) { return __builtin_bit_cast(bf16x8, v); }
DEV float ex2(float x) { return __builtin_amdgcn_exp2f(x); }   // bare v_exp_f32
DEV float max3(float a, float b, float c) {
    float d;
    asm("v_max3_f32 %0, %1, %2, %3" : "=v"(d) : "v"(a), "v"(b), "v"(c));
    return d;
}

// async global->LDS, 16B per lane; lds base must be wave-uniform, gsrc per-lane
DEV void gload16(const void* g, void* l) {
    __builtin_amdgcn_global_load_lds(
        (const __attribute__((address_space(1))) unsigned int*)g,
        (__attribute__((address_space(3))) unsigned int*)l, 16, 0, 0);
}

// ---------------- prep kernel (feat cast + weight pack fused; Q/pe in log2 domain) ----------------
// peG2 layout: [hg(8)][4096] dwords; dword = {f16 head hg*2, f16 head hg*2+1}
__global__ __launch_bounds__(256) void k_prep(const float* __restrict__ feat,
                                              const float* __restrict__ qw, const float* __restrict__ qb,
                                              const float* __restrict__ kvw, const float* __restrict__ kvb,
                                              const float* __restrict__ pew, const float* __restrict__ peb,
                                              const float* __restrict__ pret, const float* __restrict__ projw,
                                              unsigned short* __restrict__ featb,
                                              unsigned short* __restrict__ wqkv, float* __restrict__ bqkv,
                                              unsigned short* __restrict__ projwb, unsigned short* __restrict__ peG2) {
    const float l2e = 1.4426950408889634f;
    const float scale = 0.17677669529663687f * 1.4426950408889634f; // (1/sqrt(32)) * log2(e)
    int i0 = blockIdx.x * 256 + threadIdx.x;
    if (i0 < 262144) {                        // feat f32 -> bf16, 8/thread
        const float4* f4 = (const float4*)feat + (size_t)i0 * 2;
        float4 a = f4[0], c = f4[1];
        short8 o;
        o[0] = (short)f2bf(a.x); o[1] = (short)f2bf(a.y);
        o[2] = (short)f2bf(a.z); o[3] = (short)f2bf(a.w);
        o[4] = (short)f2bf(c.x); o[5] = (short)f2bf(c.y);
        o[6] = (short)f2bf(c.z); o[7] = (short)f2bf(c.w);
        ((short8*)featb)[i0] = o;
        return;
    }
    int i = i0 - 262144;
    if (i < 786432) {                         // wqkv [1536][512]; Q rows pre-scaled to log2 domain
        int o = i >> 9, k = i & 511;
        float v = (o < 512) ? qw[(o << 9) + k] * scale : kvw[((o - 512) << 9) + k];
        wqkv[i] = f2bf(v);
    } else if (i < 786432 + 262144) {
        int j = i - 786432;
        projwb[j] = f2bf(projw[j]);
    } else if (i < 786432 + 262144 + 1536) {
        int o = i - (786432 + 262144);
        bqkv[o] = (o < 512) ? qb[o] * scale : kvb[o - 512];
    } else if (i < 786432 + 262144 + 1536 + 65536) { // peG2[h>>1][t] halves, log2 domain
        int j = i - (786432 + 262144 + 1536);
        int t = j >> 4, h = j & 15;
        float s = peb[h];
#pragma unroll
        for (int u = 0; u < 5; u++) s += pret[t * 5 + u] * pew[h * 5 + u];
        peG2[(size_t)(h >> 1) * 8192 + t * 2 + (h & 1)] =
            __builtin_bit_cast(unsigned short, __float2half(s * l2e));
    }
}

// ---------------- QKV GEMM: gload_lds staging + LDS-transposed coalesced epilogue ----------------
__global__ __launch_bounds__(256) void k_qkv(const unsigned short* __restrict__ A,
                                             const unsigned short* __restrict__ Bw,
                                             const float* __restrict__ bias,
                                             unsigned short* __restrict__ Qf,
                                             unsigned short* __restrict__ Kf,
                                             unsigned short* __restrict__ Vf) {
    __shared__ __align__(16) unsigned short As[128 * 64];
    __shared__ __align__(16) unsigned short Bs[64 * 64];
    __shared__ __align__(16) unsigned short Cs[128][78];   // 19.97 KB, stride 39 dwords (odd)
    int tid = threadIdx.x, lane = tid & 63, wid = tid >> 6;
    int m0 = blockIdx.y * 128, n0 = blockIdx.x * 64;
    int wm = wid >> 1, wn = wid & 1;
    int q16 = lane & 15, g = lane >> 4;
    int lr = lane >> 3;
    int lk = ((lane & 7) ^ lr) * 8;
    f32x4 acc[4][2] = {};

    for (int k0 = 0; k0 < 512; k0 += 64) {
#pragma unroll
        for (int i = 0; i < 4; i++) {
            int ch = wid * 4 + i;
            gload16(A + (size_t)(m0 + ch * 8 + lr) * 512 + k0 + lk, As + ch * 512);
        }
#pragma unroll
        for (int i = 0; i < 2; i++) {
            int ch = wid * 2 + i;
            gload16(Bw + (size_t)(n0 + ch * 8 + lr) * 512 + k0 + lk, Bs + ch * 512);
        }
        __syncthreads();
#pragma unroll
        for (int kk = 0; kk < 64; kk += 32) {
            int c8 = (kk >> 3) + g;
            short8 a[4], b[2];
#pragma unroll
            for (int m = 0; m < 4; m++) {
                int row = wm * 64 + m * 16 + q16;
                a[m] = *(const short8*)(As + row * 64 + ((c8 ^ (q16 & 7)) << 3));
            }
#pragma unroll
            for (int n = 0; n < 2; n++) {
                int row = wn * 32 + n * 16 + q16;
                b[n] = *(const short8*)(Bs + row * 64 + ((c8 ^ (q16 & 7)) << 3));
            }
#pragma unroll
            for (int m = 0; m < 4; m++) {
#pragma unroll
                for (int n = 0; n < 2; n++)
                    acc[m][n] = __builtin_amdgcn_mfma_f32_16x16x32_bf16(asbf(a[m]), asbf(b[n]), acc[m][n], 0, 0, 0);
            }
        }
        __syncthreads();
    }

    // ---- epilogue: C -> Cs (bf16) -> 16B coalesced stores into fragment layouts ----
#pragma unroll
    for (int m = 0; m < 4; m++) {
#pragma unroll
        for (int n = 0; n < 2; n++) {
            int colL = wn * 32 + n * 16 + q16;
            float bv = bias[n0 + colL];
#pragma unroll
            for (int r = 0; r < 4; r++) {
                int rowL = wm * 64 + m * 16 + (g << 2) + r;
                Cs[rowL][colL] = f2bf(acc[m][n][r] + bv);
            }
        }
    }
    __syncthreads();
    int bx = blockIdx.x;
    if (bx < 8) {
        // Q block: 1024 horizontal 16B segments (8 consecutive d of one token)
#pragma unroll
        for (int s2 = 0; s2 < 4; s2++) {
            int seg = tid + 256 * s2;
            int row = seg >> 3, dseg = seg & 7;
            short8 v = *(const short8*)(&Cs[row][dseg * 8]);
            int rowg = m0 + row;
            int batch = rowg >> 10, nn = rowg & 1023;
            int col = n0 + dseg * 8;
            int h = col >> 5, d = col & 31;
            int bh = (batch << 4) + h;
            int qt = nn >> 5, q5l = nn & 31;
            int sub = d >> 4, hi2 = (d >> 3) & 1;
            *(short8*)(Qf + ((((size_t)(bh * 32 + qt) * 2 + sub) * 64) + hi2 * 32 + q5l) * 8) = v;
        }
    } else {
        int h = bx - 8;                      // this block covers head h's K (cols 0-31) + V (32-63)
#pragma unroll
        for (int s2 = 0; s2 < 2; s2++) {     // K: horizontal segments
            int seg = tid + 256 * s2;        // 0..511
            int row = seg >> 2, dseg = seg & 3;
            short8 v = *(const short8*)(&Cs[row][dseg * 8]);
            int rowg = m0 + row;
            int batch = rowg >> 10, nn = rowg & 1023;
            int bh = (batch << 4) + h;
            int kt = nn >> 6, ks = (nn >> 5) & 1, q5l = nn & 31;
            int d = dseg * 8;
            int half = d >> 4, hi2 = (d >> 3) & 1;
            *(short8*)(Kf + ((((size_t)((bh * 16 + kt) * 2 + ks) * 2 + half) * 64) + hi2 * 32 + q5l) * 8) = v;
        }
#pragma unroll
        for (int s2 = 0; s2 < 2; s2++) {     // V: vertical segments (8 consecutive tokens, one d)
            int seg = tid + 256 * s2;        // 0..511
            int c = seg & 31, row0 = (seg >> 5) * 8;
            unsigned short tmp[8];
#pragma unroll
            for (int i2 = 0; i2 < 8; i2++) tmp[i2] = Cs[row0 + i2][32 + c];
            int rowg = m0 + row0;
            int batch = rowg >> 10, nn = rowg & 1023;    // aligned to 8
            int bh = (batch << 4) + h;
            int kt = nn >> 6, ks = (nn >> 5) & 1, nb = nn & 31;
            int half = nb >> 4, hi2 = (nb >> 3) & 1;
            *(short8*)(Vf + ((((size_t)((bh * 16 + kt) * 2 + ks) * 2 + half) * 64) + hi2 * 32 + c) * 8) =
                *(short8*)tmp;
        }
    }
}

// ---------------- fused attention: gathers hoisted into compute phase, v_max3 max-tree ----------------
// grid 1024: b=bid&3, qt=(bid>>2)&31, hg=(bid>>7)&7
// 256 threads = 4 waves; wave w: head = hg*2+(w&1), khalf = w>>1
__global__ __launch_bounds__(256, 4) void k_attn(const unsigned short* __restrict__ Qf,
                                                 const unsigned short* __restrict__ Kf,
                                                 const unsigned short* __restrict__ Vf,
                                                 const int* __restrict__ pe_idx,
                                                 const unsigned* __restrict__ peG2,
                                                 const float* __restrict__ blank_k,
                                                 const float* __restrict__ blank_v,
                                                 unsigned short* __restrict__ attnO) {
    __shared__ unsigned peT2[4096];                      // 16 KB (read-only after init)
    __shared__ __align__(16) unsigned posS2[32 * 132];   // 16.9 KB: [q][k 0..127], stride 132

    int tid = threadIdx.x, lane = tid & 63, w = tid >> 6;
    int q5 = lane & 31, hi = lane >> 5;
    int bid = blockIdx.x;
    int b = bid & 3, qt = (bid >> 2) & 31, hg = (bid >> 7) & 7;
    int q0 = qt * 32;
    int hl = w & 1, khalf = w >> 1;
    int head = hg * 2 + hl, bh = (b << 4) + head;

    // stage peT2 (one-time): 16 coalesced b32 per thread
    {
        const unsigned* pg = peG2 + (size_t)hg * 4096;
#pragma unroll
        for (int j2 = 0; j2 < 16; j2++) {
            int r = tid + 256 * j2;
            peT2[r] = pg[r];
        }
    }

    // staging map: thread -> q row sq, k-octet kg; 4 int4 idx loads cover 128 k
    int sq = tid >> 3, kg = tid & 7;
    const int* pibase = pe_idx + ((size_t)((b << 10) + q0 + sq)) * 1024;

    short8 qf[2];
    float lb_, m_run, l_run;
    f32x16 accO = {};

    {
        const unsigned short* qb_ = Qf + ((size_t)(bh * 32 + qt) * 2) * 512 + lane * 8;
        qf[0] = *(const short8*)(qb_);
        qf[1] = *(const short8*)(qb_ + 512);
        float dot = 0.f;
#pragma unroll
        for (int sub = 0; sub < 2; sub++) {
            const float* bk = blank_k + head * 32 + sub * 16 + hi * 8;
#pragma unroll
            for (int t = 0; t < 8; t++) dot += bf2f((unsigned short)qf[sub][t]) * bk[t];
        }
        dot += __shfl_xor(dot, 32, 64);
        lb_ = dot;                           // log2 domain (qf pre-scaled by log2e)
        m_run = (khalf == 0) ? dot : -1e30f;
        l_run = (khalf == 0) ? 1.0f : 0.0f;
    }

    // prologue: id4(0) -> gather gg(0) -> write posS2(0); then id4(1)
    int4 id4[4];
    unsigned gg[4][4];
#pragma unroll
    for (int s = 0; s < 4; s++) {
        int col = (s < 2) ? (kg * 4 + 32 * s) : (512 + kg * 4 + 32 * (s - 2));
        id4[s] = *(const int4*)(pibase + col);
    }
    __syncthreads();   // peT2 ready
#pragma unroll
    for (int s = 0; s < 4; s++) {
        gg[s][0] = peT2[id4[s].x]; gg[s][1] = peT2[id4[s].y];
        gg[s][2] = peT2[id4[s].z]; gg[s][3] = peT2[id4[s].w];
    }
#pragma unroll
    for (int s = 0; s < 4; s++) {
        uint4 wv = {gg[s][0], gg[s][1], gg[s][2], gg[s][3]};
        *(uint4*)&posS2[sq * 132 + kg * 4 + 32 * s] = wv;
    }
#pragma unroll
    for (int s = 0; s < 4; s++) {          // id4 <- indices for step 1
        int col = (s < 2) ? (64 + kg * 4 + 32 * s) : (512 + 64 + kg * 4 + 32 * (s - 2));
        id4[s] = *(const int4*)(pibase + col);
    }
    __syncthreads();   // posS2(0) ready

    for (int step = 0; step < 8; step++) {
        int ktg = khalf * 8 + step;
        // S^T = K x Q^T, pos folded into MFMA C-init; rows k=(r&3)+8*(r>>2)+4*hi, col q=q5
        f32x16 st[2];
#pragma unroll
        for (int ks = 0; ks < 2; ks++) {
            f32x16 p;
#pragma unroll
            for (int rr = 0; rr < 4; rr++) {
                uint4 v = *(const uint4*)&posS2[q5 * 132 + khalf * 64 + ks * 32 + rr * 8 + 4 * hi];
                unsigned pv[4] = {v.x, v.y, v.z, v.w};
#pragma unroll
                for (int c = 0; c < 4; c++) {
                    __half2 h2 = __builtin_bit_cast(__half2, pv[c]);
                    p[rr * 4 + c] = hl ? __high2float(h2) : __low2float(h2);
                }
            }
            const unsigned short* kp = Kf + ((size_t)((bh * 16 + ktg) * 2 + ks) * 2) * 512 + lane * 8;
            short8 kf0 = *(const short8*)(kp);
            short8 kf1 = *(const short8*)(kp + 512);
            __builtin_amdgcn_s_setprio(1);
            st[ks] = __builtin_amdgcn_mfma_f32_32x32x16_bf16(asbf(kf0), asbf(qf[0]), p, 0, 0, 0);
            st[ks] = __builtin_amdgcn_mfma_f32_32x32x16_bf16(asbf(kf1), asbf(qf[1]), st[ks], 0, 0, 0);
            __builtin_amdgcn_s_setprio(0);
        }
        // tile max: v_max3 tree (32 vals -> 11 -> 4 -> 1), ~16 ops vs 31 fmax
        float tm[11];
#pragma unroll
        for (int i = 0; i < 8; i++) tm[i] = max3(st[0][i], st[0][i + 8], st[1][i]);
        tm[8] = max3(st[1][8], st[1][9], st[1][10]);
        tm[9] = max3(st[1][11], st[1][12], st[1][13]);
        tm[10] = fmaxf(st[1][14], st[1][15]);
        float a0 = max3(tm[0], tm[1], tm[2]);
        float a1 = max3(tm[3], tm[4], tm[5]);
        float a2 = max3(tm[6], tm[7], tm[8]);
        float a3 = fmaxf(tm[9], tm[10]);
        float mx = fmaxf(max3(a0, a1, a2), a3);
        mx = fmaxf(mx, __shfl_xor(mx, 32, 64));
        // defer-max (T13), log2 domain: P bounded by 2^8
        if (!__all(mx <= m_run + 8.0f)) {
            float mn = fmaxf(m_run, mx);
            float fac = ex2(m_run - mn);
            m_run = mn;
            l_run *= fac;
#pragma unroll
            for (int r = 0; r < 16; r++) {
                int qrow = (r & 3) + 8 * (r >> 2) + 4 * hi;
                float facr = __shfl(fac, qrow, 64);
                accO[r] *= facr;
            }
        }
#pragma unroll
        for (int ks = 0; ks < 2; ks++)
#pragma unroll
            for (int r = 0; r < 16; r++)
                st[ks][r] = ex2(st[ks][r] - m_run);
        // sum: tree reduction
        float ts[16];
#pragma unroll
        for (int i = 0; i < 16; i++) ts[i] = st[0][i] + st[1][i];
#pragma unroll
        for (int i = 0; i < 8; i++) ts[i] += ts[i + 8];
#pragma unroll
        for (int i = 0; i < 4; i++) ts[i] += ts[i + 4];
        float sum = (ts[0] + ts[1]) + (ts[2] + ts[3]);
        sum += __shfl_xor(sum, 32, 64);
        l_run += sum;
        // P -> A-frag via v_cvt_pk_bf16_f32 + permlane32_swap (T12), then PV
#pragma unroll
        for (int ks = 0; ks < 2; ks++) {
            unsigned pk_[8];
#pragma unroll
            for (int i = 0; i < 8; i++) {
                float plo = st[ks][2 * i], phi = st[ks][2 * i + 1];
                asm("v_cvt_pk_bf16_f32 %0, %1, %2" : "=v"(pk_[i]) : "v"(plo), "v"(phi));
            }
            asm("v_permlane32_swap_b32 %0, %1" : "+v"(pk_[0]), "+v"(pk_[2]));
            asm("v_permlane32_swap_b32 %0, %1" : "+v"(pk_[1]), "+v"(pk_[3]));
            asm("v_permlane32_swap_b32 %0, %1" : "+v"(pk_[4]), "+v"(pk_[6]));
            asm("v_permlane32_swap_b32 %0, %1" : "+v"(pk_[5]), "+v"(pk_[7]));
            uint4 u0 = {pk_[0], pk_[1], pk_[2], pk_[3]};
            uint4 u1 = {pk_[4], pk_[5], pk_[6], pk_[7]};
            short8 pa0 = __builtin_bit_cast(short8, u0);
            short8 pa1 = __builtin_bit_cast(short8, u1);
            const unsigned short* vp = Vf + ((size_t)((bh * 16 + ktg) * 2 + ks) * 2) * 512 + lane * 8;
            short8 vf0 = *(const short8*)(vp);
            short8 vf1 = *(const short8*)(vp + 512);
            __builtin_amdgcn_s_setprio(1);
            accO = __builtin_amdgcn_mfma_f32_32x32x16_bf16(asbf(pa0), asbf(vf0), accO, 0, 0, 0);
            accO = __builtin_amdgcn_mfma_f32_32x32x16_bf16(asbf(pa1), asbf(vf1), accO, 0, 0, 0);
            __builtin_amdgcn_s_setprio(0);
        }
        // gather next step's pos values from peT2 into regs (overlaps this compute tail;
        // peT2 is read-only so no hazard with other waves)
        if (step < 7) {
#pragma unroll
            for (int s = 0; s < 4; s++) {
                gg[s][0] = peT2[id4[s].x]; gg[s][1] = peT2[id4[s].y];
                gg[s][2] = peT2[id4[s].z]; gg[s][3] = peT2[id4[s].w];
            }
        }
        __syncthreads();   // posS2(step) fully consumed by all waves
        if (step < 7) {
            // short staging window: 4 b128 writes + issue id4(step+2) global loads
#pragma unroll
            for (int s = 0; s < 4; s++) {
                uint4 wv = {gg[s][0], gg[s][1], gg[s][2], gg[s][3]};
                *(uint4*)&posS2[sq * 132 + kg * 4 + 32 * s] = wv;
            }
            if (step < 6) {
#pragma unroll
                for (int s = 0; s < 4; s++) {
                    int col = (s < 2) ? ((step + 2) * 64 + kg * 4 + 32 * s)
                                      : (512 + (step + 2) * 64 + kg * 4 + 32 * (s - 2));
                    id4[s] = *(const int4*)(pibase + col);
                }
            }
            __syncthreads();   // posS2(step+1) ready
        }
    }

    // ---- in-block split-k combine (posS2 reused as scratch), log2 domain ----
    float* fb = (float*)posS2;           // comb[hl][lane][17] then mS[2][32], lS[2][32]
    float* mS = fb + 2176;
    float* lS = mS + 64;
    if (khalf == 1) {
#pragma unroll
        for (int r = 0; r < 16; r++)
            fb[(hl * 64 + lane) * 17 + r] = accO[r];
        if (hi == 0) {
            mS[hl * 32 + q5] = m_run;
            lS[hl * 32 + q5] = l_run;
        }
    }
    __syncthreads();
    if (khalf == 0) {
        float mB = mS[hl * 32 + q5], lB = lS[hl * 32 + q5];
        float M = fmaxf(m_run, mB);
        float eA = ex2(m_run - M), eB = ex2(mB - M);
        float L = l_run * eA + lB * eB;
        float inv = 1.0f / L;
        float bw = ex2(lb_ - M) * inv;
        float bv = blank_v[head * 32 + q5];
#pragma unroll
        for (int r = 0; r < 16; r++) {
            int qrow = (r & 3) + 8 * (r >> 2) + 4 * hi;
            float eA_r = __shfl(eA, qrow, 64);
            float eB_r = __shfl(eB, qrow, 64);
            float inv_r = __shfl(inv, qrow, 64);
            float bw_r = __shfl(bw, qrow, 64);
            float accB = fb[(hl * 64 + lane) * 17 + r];
            float ov = (accO[r] * eA_r + accB * eB_r) * inv_r + bw_r * bv;
            attnO[((size_t)((b << 10) + q0 + qrow)) * 512 + head * 32 + q5] = f2bf(ov);
        }
    }
}

// ---------------- final projection GEMM: 64x64 tiles, grid 512 (2/CU) ----------------
__global__ __launch_bounds__(256) void k_proj(const unsigned short* __restrict__ A,
                                              const unsigned short* __restrict__ Bw,
                                              const float* __restrict__ bias,
                                              float* __restrict__ out) {
    __shared__ __align__(16) unsigned short As[64 * 64];
    __shared__ __align__(16) unsigned short Bs[64 * 64];
    int tid = threadIdx.x, lane = tid & 63, wid = tid >> 6;
    int m0 = blockIdx.y * 64, n0 = blockIdx.x * 64;
    int wm = wid >> 1, wn = wid & 1;
    int q16 = lane & 15, g = lane >> 4;
    int lr = lane >> 3;
    int lk = ((lane & 7) ^ lr) * 8;
    f32x4 acc[2][2] = {};

    for (int k0 = 0; k0 < 512; k0 += 64) {
#pragma unroll
        for (int i = 0; i < 2; i++) {
            int ch = wid * 2 + i;
            gload16(A + (size_t)(m0 + ch * 8 + lr) * 512 + k0 + lk, As + ch * 512);
            gload16(Bw + (size_t)(n0 + ch * 8 + lr) * 512 + k0 + lk, Bs + ch * 512);
        }
        __syncthreads();
#pragma unroll
        for (int kk = 0; kk < 64; kk += 32) {
            int c8 = (kk >> 3) + g;
            short8 a[2], b[2];
#pragma unroll
            for (int m = 0; m < 2; m++) {
                int row = wm * 32 + m * 16 + q16;
                a[m] = *(const short8*)(As + row * 64 + ((c8 ^ (q16 & 7)) << 3));
            }
#pragma unroll
            for (int n = 0; n < 2; n++) {
                int row = wn * 32 + n * 16 + q16;
                b[n] = *(const short8*)(Bs + row * 64 + ((c8 ^ (q16 & 7)) << 3));
            }
#pragma unroll
            for (int m = 0; m < 2; m++) {
#pragma unroll
                for (int n = 0; n < 2; n++)
                    acc[m][n] = __builtin_amdgcn_mfma_f32_16x16x32_bf16(asbf(a[m]), asbf(b[n]), acc[m][n], 0, 0, 0);
            }
        }
        __syncthreads();
    }
#pragma unroll
    for (int m = 0; m < 2; m++) {
#pragma unroll
        for (int n = 0; n < 2; n++) {
            int col = n0 + wn * 32 + n * 16 + q16;
            float bv = bias[col];
#pragma unroll
            for (int r = 0; r < 4; r++) {
                int row = m0 + wm * 32 + m * 16 + (g << 2) + r;
                out[(size_t)row * 512 + col] = acc[m][n][r] + bv;
            }
        }
    }
}

extern "C" void kernel_launch(void* const* d_in, const int* in_sizes, int n_in,
                              void* d_out, int out_size, void* d_ws, size_t ws_size,
                              hipStream_t stream) {
    const float* feat    = (const float*)d_in[0];
    const int*   pe_idx  = (const int*)d_in[3];
    const float* pret    = (const float*)d_in[5];
    const float* qw      = (const float*)d_in[6];
    const float* qb      = (const float*)d_in[7];
    const float* kvw     = (const float*)d_in[8];
    const float* kvb     = (const float*)d_in[9];
    const float* pew     = (const float*)d_in[10];
    const float* peb     = (const float*)d_in[11];
    const float* blank_k = (const float*)d_in[12];
    const float* blank_v = (const float*)d_in[13];
    const float* projw   = (const float*)d_in[14];
    const float* projb   = (const float*)d_in[15];

    char* ws = (char*)d_ws;
    unsigned short* featb  = (unsigned short*)(ws);                  // 4 MB (reused as attnO)
    unsigned short* wqkv   = (unsigned short*)(ws + 4194304);        // 1.5 MB
    unsigned short* projwb = (unsigned short*)(ws + 5767168);        // 0.5 MB
    float*          bqkv   = (float*)(ws + 6291456);                 // 6 KB
    unsigned short* peG2   = (unsigned short*)(ws + 6297600);        // 128 KB
    unsigned short* Qf     = (unsigned short*)(ws + 6428672);        // 4 MB
    unsigned short* Kf     = (unsigned short*)(ws + 10622976);       // 4 MB
    unsigned short* Vf     = (unsigned short*)(ws + 14817280);       // 4 MB
    unsigned short* attnO  = featb;                                  // alias (featb dead after k_qkv)

    k_prep<<<dim3(5382), dim3(256), 0, stream>>>(feat, qw, qb, kvw, kvb, pew, peb, pret, projw,
                                                 featb, wqkv, bqkv, projwb, peG2);
    k_qkv<<<dim3(24, 32), dim3(256), 0, stream>>>(featb, wqkv, bqkv, Qf, Kf, Vf);
    k_attn<<<dim3(1024), dim3(256), 0, stream>>>(Qf, Kf, Vf, pe_idx, (const unsigned*)peG2,
                                                 blank_k, blank_v, attnO);
    k_proj<<<dim3(8, 64), dim3(256), 0, stream>>>(attnO, projwb, projb, (float*)d_out);
}